// Round 1
// baseline (2404.214 us; speedup 1.0000x reference)
//
#include <hip/hip_runtime.h>
#include <math.h>

#define NVEC 2000
#define DD   768
#define HH   1024
#define KNUM 250
#define MSEL 400
#define MR   399     // m-1 rows
#define OUTW 251

__device__ __forceinline__ float waveSum(float p) {
#pragma unroll
  for (int off = 32; off >= 1; off >>= 1) p += __shfl_xor(p, off, 64);
  return p;
}
__device__ __forceinline__ float waveMax(float p) {
#pragma unroll
  for (int off = 32; off >= 1; off >>= 1) p = fmaxf(p, __shfl_xor(p, off, 64));
  return p;
}

// ---------------- K1: scores = relu(V @ Wm1 + bm1) @ wm2 + bm2 ----------------
// 8 rows per block, 256 threads, each thread owns 4 contiguous H-columns (float4).
__global__ __launch_bounds__(256) void scores_kernel(
    const float* __restrict__ vectors, const float* __restrict__ Wm1,
    const float* __restrict__ bm1, const float* __restrict__ wm2,
    const float* __restrict__ bm2, float* __restrict__ scores) {
  __shared__ float vrow[8 * DD];
  __shared__ float red[4];
  const int tid = threadIdx.x;
  const int base = blockIdx.x * 8;
  // rows are contiguous in global memory -> flat coalesced stage
  for (int idx = tid; idx < 8 * DD; idx += 256)
    vrow[idx] = vectors[base * DD + idx];
  __syncthreads();
  float acc[8][4];
#pragma unroll
  for (int r = 0; r < 8; ++r)
#pragma unroll
    for (int c = 0; c < 4; ++c) acc[r][c] = 0.f;
  for (int d = 0; d < DD; ++d) {
    const float4 w = ((const float4*)(Wm1 + d * HH))[tid];
#pragma unroll
    for (int r = 0; r < 8; ++r) {
      const float a = vrow[r * DD + d];
      acc[r][0] += a * w.x; acc[r][1] += a * w.y;
      acc[r][2] += a * w.z; acc[r][3] += a * w.w;
    }
  }
  const float4 b = ((const float4*)bm1)[tid];
  const float4 m = ((const float4*)wm2)[tid];
  const float sc = bm2[0];
  for (int r = 0; r < 8; ++r) {
    float p = fmaxf(acc[r][0] + b.x, 0.f) * m.x + fmaxf(acc[r][1] + b.y, 0.f) * m.y
            + fmaxf(acc[r][2] + b.z, 0.f) * m.z + fmaxf(acc[r][3] + b.w, 0.f) * m.w;
    p = waveSum(p);
    if ((tid & 63) == 0) red[tid >> 6] = p;
    __syncthreads();
    if (tid == 0) scores[base + r] = red[0] + red[1] + red[2] + red[3] + sc;
    __syncthreads();
  }
}

// ---------------- K2: bitonic sort of (score,index), descending score, tie idx asc ----------------
// Matches argsort(-scores) stable semantics (strict total order).
__global__ __launch_bounds__(1024) void topsort_kernel(
    const float* __restrict__ scores, int* __restrict__ top) {
  __shared__ float ks[2048];
  __shared__ int   ki[2048];
  const int tid = threadIdx.x;
  for (int e = tid; e < 2048; e += 1024) {
    ks[e] = (e < NVEC) ? scores[e] : -INFINITY;
    ki[e] = e;
  }
  __syncthreads();
  for (int k = 2; k <= 2048; k <<= 1) {
    for (int j = k >> 1; j > 0; j >>= 1) {
      for (int e = tid; e < 2048; e += 1024) {
        const int l = e ^ j;
        if (l > e) {
          const float s1 = ks[e], s2 = ks[l];
          const int i1 = ki[e], i2 = ki[l];
          const bool first = (s1 > s2) || (s1 == s2 && i1 < i2);
          const bool up = ((e & k) == 0);
          if (up ? !first : first) {
            ks[e] = s2; ks[l] = s1; ki[e] = i2; ki[l] = i1;
          }
        }
      }
      __syncthreads();
    }
  }
  if (tid < MSEL) top[tid] = ki[tid];
}

// ---------------- K3: lexsort by (start,end,pos) asc, then reverse ----------------
// Matches jnp.lexsort((ends, starts))[::-1] incl. stable tie-break.
__global__ __launch_bounds__(256) void lexsort_kernel(
    const int* __restrict__ top, const int* __restrict__ sst,
    const int* __restrict__ sen, const float* __restrict__ scores,
    int* __restrict__ perm, float* __restrict__ sfin) {
  __shared__ int s_st[512], s_en[512], s_j[512];
  const int tid = threadIdx.x;
  for (int e = tid; e < 512; e += 256) {
    if (e < MSEL) { const int ti = top[e]; s_st[e] = sst[ti]; s_en[e] = sen[ti]; }
    else { s_st[e] = 0x7fffffff; s_en[e] = 0x7fffffff; }
    s_j[e] = e;
  }
  __syncthreads();
  for (int k = 2; k <= 512; k <<= 1) {
    for (int j = k >> 1; j > 0; j >>= 1) {
      for (int e = tid; e < 512; e += 256) {
        const int l = e ^ j;
        if (l > e) {
          const int a0 = s_st[e], a1 = s_en[e], a2 = s_j[e];
          const int b0 = s_st[l], b1 = s_en[l], b2 = s_j[l];
          const bool first = (a0 < b0) || (a0 == b0 && (a1 < b1 || (a1 == b1 && a2 < b2)));
          const bool up = ((e & k) == 0);
          if (up ? !first : first) {
            s_st[e] = b0; s_en[e] = b1; s_j[e] = b2;
            s_st[l] = a0; s_en[l] = a1; s_j[l] = a2;
          }
        }
      }
      __syncthreads();
    }
  }
  for (int i = tid; i < MSEL; i += 256) {
    const int src = s_j[MSEL - 1 - i];   // reversal of ascending lexsort
    const int vi = top[src];
    perm[i] = vi;
    sfin[i] = scores[vi];
  }
}

// ---------------- K4: Ha = v@Wa (399 rows), Hv = v@Wb (400 rows) ----------------
__global__ __launch_bounds__(256) void hab_kernel(
    const float* __restrict__ vectors, const float* __restrict__ Wp1,
    const int* __restrict__ perm, float* __restrict__ Ha, float* __restrict__ Hv) {
  __shared__ float vrow[8 * DD];
  const int tid = threadIdx.x;
  const int base = blockIdx.x * 8;
  for (int r = 0; r < 8; ++r) {
    const int pi = perm[base + r];
    for (int d = tid; d < DD; d += 256) vrow[r * DD + d] = vectors[pi * DD + d];
  }
  __syncthreads();
  float acca[8][4], accb[8][4];
#pragma unroll
  for (int r = 0; r < 8; ++r)
#pragma unroll
    for (int c = 0; c < 4; ++c) { acca[r][c] = 0.f; accb[r][c] = 0.f; }
  const float* Wa = Wp1;
  const float* Wb = Wp1 + DD * HH;
  for (int d = 0; d < DD; ++d) {
    const float4 wa = ((const float4*)(Wa + d * HH))[tid];
    const float4 wb = ((const float4*)(Wb + d * HH))[tid];
#pragma unroll
    for (int r = 0; r < 8; ++r) {
      const float a = vrow[r * DD + d];
      acca[r][0] += a * wa.x; acca[r][1] += a * wa.y;
      acca[r][2] += a * wa.z; acca[r][3] += a * wa.w;
      accb[r][0] += a * wb.x; accb[r][1] += a * wb.y;
      accb[r][2] += a * wb.z; accb[r][3] += a * wb.w;
    }
  }
  for (int r = 0; r < 8; ++r) {
    const int row = base + r;
    ((float4*)(Hv + row * HH))[tid] = make_float4(accb[r][0], accb[r][1], accb[r][2], accb[r][3]);
    if (row < MR)
      ((float4*)(Ha + row * HH))[tid] = make_float4(acca[r][0], acca[r][1], acca[r][2], acca[r][3]);
  }
}

// ---------------- K5: pairwise logits (the 157 GFLOP einsum, fused epilogue) ----------------
// block = (anaphor i, k-tile of 16). x[d][kk] = a_i[d]*b_j[d] staged in LDS.
__global__ __launch_bounds__(256) void pair_kernel(
    const float* __restrict__ vectors, const float* __restrict__ Wp1,
    const float* __restrict__ bp1, const float* __restrict__ wp2,
    const float* __restrict__ bp2, const int* __restrict__ perm,
    const float* __restrict__ sfin, const float* __restrict__ Ha,
    const float* __restrict__ Hv, float* __restrict__ out) {
  __shared__ __align__(16) float xs[DD][16];
  __shared__ float aL[DD];
  __shared__ float red[4];
  const int tid = threadIdx.x;
  const int i = blockIdx.x;
  const int kt = blockIdx.y;
  const int pi = perm[i];
  for (int d = tid; d < DD; d += 256) aL[d] = vectors[pi * DD + d];
  __syncthreads();
  for (int kk = 0; kk < 16; ++kk) {
    int jidx = i + 1 + kt * 16 + kk;
    if (jidx > MR) jidx = MR;          // clamp (covers invalid + k-overhang)
    const int pj = perm[jidx];
    for (int d = tid; d < DD; d += 256) xs[d][kk] = aL[d] * vectors[pj * DD + d];
  }
  __syncthreads();
  float acc[16][4];
#pragma unroll
  for (int kk = 0; kk < 16; ++kk)
#pragma unroll
    for (int c = 0; c < 4; ++c) acc[kk][c] = 0.f;
  const float* Wab = Wp1 + 2 * DD * HH;
  for (int d = 0; d < DD; ++d) {
    const float4 w = ((const float4*)(Wab + d * HH))[tid];
    const float4* xp = (const float4*)(&xs[d][0]);
    const float4 x0 = xp[0], x1 = xp[1], x2 = xp[2], x3 = xp[3];
    const float xv[16] = {x0.x, x0.y, x0.z, x0.w, x1.x, x1.y, x1.z, x1.w,
                          x2.x, x2.y, x2.z, x2.w, x3.x, x3.y, x3.z, x3.w};
#pragma unroll
    for (int kk = 0; kk < 16; ++kk) {
      acc[kk][0] += xv[kk] * w.x; acc[kk][1] += xv[kk] * w.y;
      acc[kk][2] += xv[kk] * w.z; acc[kk][3] += xv[kk] * w.w;
    }
  }
  const float4 ha = ((const float4*)(Ha + i * HH))[tid];
  const float4 b  = ((const float4*)bp1)[tid];
  const float4 wp = ((const float4*)wp2)[tid];
  const float s_i = sfin[i];
  const float bp2v = bp2[0];
  for (int kk = 0; kk < 16; ++kk) {
    const int k = kt * 16 + kk;
    if (k >= KNUM) break;              // uniform across block
    const int jidx = i + 1 + k;
    const bool valid = jidx < MSEL;
    const int jc = valid ? jidx : MR;
    const float4 hv = ((const float4*)(Hv + jc * HH))[tid];
    float p = fmaxf(acc[kk][0] + ha.x + hv.x + b.x, 0.f) * wp.x
            + fmaxf(acc[kk][1] + ha.y + hv.y + b.y, 0.f) * wp.y
            + fmaxf(acc[kk][2] + ha.z + hv.z + b.z, 0.f) * wp.z
            + fmaxf(acc[kk][3] + ha.w + hv.w + b.w, 0.f) * wp.w;
    p = waveSum(p);
    if ((tid & 63) == 0) red[tid >> 6] = p;
    __syncthreads();
    if (tid == 0) {
      const float tot = red[0] + red[1] + red[2] + red[3] + bp2v + sfin[jc] + s_i;
      out[i * OUTW + k] = valid ? tot : -INFINITY;
    }
    __syncthreads();
  }
}

// ---------------- K6: softmax over 251 cols (col 250 is implicit 0-logit), in place ----------------
__global__ __launch_bounds__(256) void softmax_kernel(float* __restrict__ out) {
  __shared__ float red[4];
  const int i = blockIdx.x, tid = threadIdx.x;
  float v;
  if (tid < KNUM) v = out[i * OUTW + tid];
  else if (tid == KNUM) v = 0.f;
  else v = -INFINITY;
  float mx = waveMax(v);
  if ((tid & 63) == 0) red[tid >> 6] = mx;
  __syncthreads();
  const float m = fmaxf(fmaxf(red[0], red[1]), fmaxf(red[2], red[3]));
  __syncthreads();
  const float e = (tid <= KNUM) ? expf(v - m) : 0.f;   // exp(-inf - m) = 0
  float s = waveSum(e);
  if ((tid & 63) == 0) red[tid >> 6] = s;
  __syncthreads();
  const float tot = red[0] + red[1] + red[2] + red[3];
  if (tid <= KNUM) out[i * OUTW + tid] = e / tot;
}

extern "C" void kernel_launch(void* const* d_in, const int* in_sizes, int n_in,
                              void* d_out, int out_size, void* d_ws, size_t ws_size,
                              hipStream_t stream) {
  const float* vectors = (const float*)d_in[0];
  const float* Wm1 = (const float*)d_in[1];
  const float* bm1 = (const float*)d_in[2];
  const float* wm2 = (const float*)d_in[3];
  const float* bm2 = (const float*)d_in[4];
  const float* Wp1 = (const float*)d_in[5];
  const float* bp1 = (const float*)d_in[6];
  const float* wp2 = (const float*)d_in[7];
  const float* bp2 = (const float*)d_in[8];
  const int* sst = (const int*)d_in[9];
  const int* sen = (const int*)d_in[10];
  // d_in[11] = t (=1000 on device); m = int(0.4*t) = 400 hardcoded as MSEL.
  float* out = (float*)d_out;
  char* ws = (char*)d_ws;

  float* scores = (float*)(ws);                                   // 2000 f32
  int*   top    = (int*)(ws + 8192);                              // 400 i32
  int*   perm   = (int*)(ws + 10240);                             // 400 i32
  float* sfin   = (float*)(ws + 12288);                           // 400 f32
  float* Ha     = (float*)(ws + 16384);                           // 400*1024 f32 (399 used)
  float* Hv     = (float*)(ws + 16384 + (size_t)MSEL * HH * 4);   // 400*1024 f32

  scores_kernel<<<NVEC / 8, 256, 0, stream>>>(vectors, Wm1, bm1, wm2, bm2, scores);
  topsort_kernel<<<1, 1024, 0, stream>>>(scores, top);
  lexsort_kernel<<<1, 256, 0, stream>>>(top, sst, sen, scores, perm, sfin);
  hab_kernel<<<MSEL / 8, 256, 0, stream>>>(vectors, Wp1, perm, Ha, Hv);
  pair_kernel<<<dim3(MR, 16), 256, 0, stream>>>(vectors, Wp1, bp1, wp2, bp2, perm, sfin, Ha, Hv, out);
  softmax_kernel<<<MR, 256, 0, stream>>>(out);
}

// Round 3
// 784.362 us; speedup vs baseline: 3.0652x; 3.0652x over previous
//
#include <hip/hip_runtime.h>
#include <hip/hip_bf16.h>
#include <math.h>

#define NVEC 2000
#define DD   768
#define HH   1024
#define KNUM 250
#define MSEL 400
#define MR   399     // m-1 rows
#define OUTW 251
#define PPAD 256                 // padded antecedents per anaphor
#define NPAIR (MR * PPAD)        // 102144 padded pair rows
#define BM 128
#define BN 128
#define BK 64
#define NKT (DD / BK)            // 12

typedef short  bf16x8 __attribute__((ext_vector_type(8)));
typedef float  f32x4  __attribute__((ext_vector_type(4)));

__device__ __forceinline__ float waveSum(float p) {
#pragma unroll
  for (int off = 32; off >= 1; off >>= 1) p += __shfl_xor(p, off, 64);
  return p;
}
__device__ __forceinline__ float waveMax(float p) {
#pragma unroll
  for (int off = 32; off >= 1; off >>= 1) p = fmaxf(p, __shfl_xor(p, off, 64));
  return p;
}
// round-to-nearest-even f32 -> bf16 bits (finite inputs only)
__device__ __forceinline__ ushort f2bfu(float f) {
  union { float f; unsigned u; } v; v.f = f;
  return (ushort)((v.u + 0x7fffu + ((v.u >> 16) & 1u)) >> 16);
}

// ---------------- K1: scores = relu(V @ Wm1 + bm1) @ wm2 + bm2 ----------------
__global__ __launch_bounds__(256) void scores_kernel(
    const float* __restrict__ vectors, const float* __restrict__ Wm1,
    const float* __restrict__ bm1, const float* __restrict__ wm2,
    const float* __restrict__ bm2, float* __restrict__ scores) {
  __shared__ float vrow[8 * DD];
  __shared__ float red[4];
  const int tid = threadIdx.x;
  const int base = blockIdx.x * 8;
  for (int idx = tid; idx < 8 * DD; idx += 256)
    vrow[idx] = vectors[base * DD + idx];
  __syncthreads();
  float acc[8][4];
#pragma unroll
  for (int r = 0; r < 8; ++r)
#pragma unroll
    for (int c = 0; c < 4; ++c) acc[r][c] = 0.f;
  for (int d = 0; d < DD; ++d) {
    const float4 w = ((const float4*)(Wm1 + d * HH))[tid];
#pragma unroll
    for (int r = 0; r < 8; ++r) {
      const float a = vrow[r * DD + d];
      acc[r][0] += a * w.x; acc[r][1] += a * w.y;
      acc[r][2] += a * w.z; acc[r][3] += a * w.w;
    }
  }
  const float4 b = ((const float4*)bm1)[tid];
  const float4 m = ((const float4*)wm2)[tid];
  const float sc = bm2[0];
  for (int r = 0; r < 8; ++r) {
    float p = fmaxf(acc[r][0] + b.x, 0.f) * m.x + fmaxf(acc[r][1] + b.y, 0.f) * m.y
            + fmaxf(acc[r][2] + b.z, 0.f) * m.z + fmaxf(acc[r][3] + b.w, 0.f) * m.w;
    p = waveSum(p);
    if ((tid & 63) == 0) red[tid >> 6] = p;
    __syncthreads();
    if (tid == 0) scores[base + r] = red[0] + red[1] + red[2] + red[3] + sc;
    __syncthreads();
  }
}

// ---------------- K2: bitonic sort (score desc, idx asc) -> top 400 ----------------
__global__ __launch_bounds__(1024) void topsort_kernel(
    const float* __restrict__ scores, int* __restrict__ top) {
  __shared__ float ks[2048];
  __shared__ int   ki[2048];
  const int tid = threadIdx.x;
  for (int e = tid; e < 2048; e += 1024) {
    ks[e] = (e < NVEC) ? scores[e] : -INFINITY;
    ki[e] = e;
  }
  __syncthreads();
  for (int k = 2; k <= 2048; k <<= 1) {
    for (int j = k >> 1; j > 0; j >>= 1) {
      for (int e = tid; e < 2048; e += 1024) {
        const int l = e ^ j;
        if (l > e) {
          const float s1 = ks[e], s2 = ks[l];
          const int i1 = ki[e], i2 = ki[l];
          const bool first = (s1 > s2) || (s1 == s2 && i1 < i2);
          const bool up = ((e & k) == 0);
          if (up ? !first : first) {
            ks[e] = s2; ks[l] = s1; ki[e] = i2; ki[l] = i1;
          }
        }
      }
      __syncthreads();
    }
  }
  if (tid < MSEL) top[tid] = ki[tid];
}

// ---------------- K3: lexsort by (start,end,pos) asc, reversed ----------------
__global__ __launch_bounds__(256) void lexsort_kernel(
    const int* __restrict__ top, const int* __restrict__ sst,
    const int* __restrict__ sen, const float* __restrict__ scores,
    int* __restrict__ perm, float* __restrict__ sfin) {
  __shared__ int s_st[512], s_en[512], s_j[512];
  const int tid = threadIdx.x;
  for (int e = tid; e < 512; e += 256) {
    if (e < MSEL) { const int ti = top[e]; s_st[e] = sst[ti]; s_en[e] = sen[ti]; }
    else { s_st[e] = 0x7fffffff; s_en[e] = 0x7fffffff; }
    s_j[e] = e;
  }
  __syncthreads();
  for (int k = 2; k <= 512; k <<= 1) {
    for (int j = k >> 1; j > 0; j >>= 1) {
      for (int e = tid; e < 512; e += 256) {
        const int l = e ^ j;
        if (l > e) {
          const int a0 = s_st[e], a1 = s_en[e], a2 = s_j[e];
          const int b0 = s_st[l], b1 = s_en[l], b2 = s_j[l];
          const bool first = (a0 < b0) || (a0 == b0 && (a1 < b1 || (a1 == b1 && a2 < b2)));
          const bool up = ((e & k) == 0);
          if (up ? !first : first) {
            s_st[e] = b0; s_en[e] = b1; s_j[e] = b2;
            s_st[l] = a0; s_en[l] = a1; s_j[l] = a2;
          }
        }
      }
      __syncthreads();
    }
  }
  for (int i = tid; i < MSEL; i += 256) {
    const int src = s_j[MSEL - 1 - i];
    const int vi = top[src];
    perm[i] = vi;
    sfin[i] = scores[vi];
  }
}

// ---------------- K4: Ha = v@Wa, Hv = v@Wb, and gather Vp = v[perm] ----------------
__global__ __launch_bounds__(256) void hab_kernel(
    const float* __restrict__ vectors, const float* __restrict__ Wp1,
    const int* __restrict__ perm, float* __restrict__ Ha, float* __restrict__ Hv,
    float* __restrict__ Vp) {
  __shared__ float vrow[8 * DD];
  const int tid = threadIdx.x;
  const int base = blockIdx.x * 8;
  for (int r = 0; r < 8; ++r) {
    const int pi = perm[base + r];
    for (int d = tid; d < DD; d += 256) {
      const float val = vectors[pi * DD + d];
      vrow[r * DD + d] = val;
      Vp[(size_t)(base + r) * DD + d] = val;
    }
  }
  __syncthreads();
  float acca[8][4], accb[8][4];
#pragma unroll
  for (int r = 0; r < 8; ++r)
#pragma unroll
    for (int c = 0; c < 4; ++c) { acca[r][c] = 0.f; accb[r][c] = 0.f; }
  const float* Wa = Wp1;
  const float* Wb = Wp1 + DD * HH;
  for (int d = 0; d < DD; ++d) {
    const float4 wa = ((const float4*)(Wa + d * HH))[tid];
    const float4 wb = ((const float4*)(Wb + d * HH))[tid];
#pragma unroll
    for (int r = 0; r < 8; ++r) {
      const float a = vrow[r * DD + d];
      acca[r][0] += a * wa.x; acca[r][1] += a * wa.y;
      acca[r][2] += a * wa.z; acca[r][3] += a * wa.w;
      accb[r][0] += a * wb.x; accb[r][1] += a * wb.y;
      accb[r][2] += a * wb.z; accb[r][3] += a * wb.w;
    }
  }
  for (int r = 0; r < 8; ++r) {
    const int row = base + r;
    ((float4*)(Hv + (size_t)row * HH))[tid] = make_float4(accb[r][0], accb[r][1], accb[r][2], accb[r][3]);
    if (row < MR)
      ((float4*)(Ha + (size_t)row * HH))[tid] = make_float4(acca[r][0], acca[r][1], acca[r][2], acca[r][3]);
  }
}

// ---------------- K4b: Wt[n][k] = bf16(Wab[k][n]) (transpose + cast, once) ----------------
__global__ __launch_bounds__(256) void wt_kernel(
    const float* __restrict__ Wp1, ushort* __restrict__ Wt) {
  __shared__ float tile[64][65];
  const int kb = blockIdx.x;   // 12 tiles over K=768
  const int nb = blockIdx.y;   // 16 tiles over N=1024
  const float* Wab = Wp1 + 2 * DD * HH;
  for (int idx = threadIdx.x; idx < 64 * 64; idx += 256) {
    const int kk = idx >> 6, nn = idx & 63;
    tile[kk][nn] = Wab[(size_t)(kb * 64 + kk) * HH + nb * 64 + nn];
  }
  __syncthreads();
  for (int idx = threadIdx.x; idx < 64 * 64; idx += 256) {
    const int nn = idx >> 6, kk = idx & 63;
    Wt[(size_t)(nb * 64 + nn) * DD + kb * 64 + kk] = f2bfu(tile[kk][nn]);
  }
}

// ---------------- K5: pairwise einsum as bf16 MFMA GEMM, fused relu-dot epilogue ----------------
// Block: 128 pair-rows (one anaphor i, half of its padded 256 k's) x 128 h-cols.
// Waves form a 2x2 (wr,wc) grid over the 128x128 tile. Per-row epilogue partials
// from the two wc-waves are combined via LDS (redp) before the single store.
__global__ __launch_bounds__(256) void pair_kernel(
    const float* __restrict__ Vp, const ushort* __restrict__ Wt,
    const float* __restrict__ bp1, const float* __restrict__ wp2,
    const float* __restrict__ Ha, const float* __restrict__ Hv,
    float* __restrict__ pp) {
  __shared__ float aL[DD];
  __shared__ int jrs[BM];
  __shared__ __align__(16) ushort As[BM * BK];
  __shared__ __align__(16) ushort Bs[BN * BK];
  __shared__ float redp[BM][2];
  const int tid = threadIdx.x;
  const int mb = blockIdx.x;          // 0..797  (i*2 + khalf)
  const int nb = blockIdx.y;          // 0..7
  const int i = mb >> 1;
  const int khalf = mb & 1;
  const int n0 = nb * BN;
  const int lane = tid & 63;
  const int wid = tid >> 6;
  const int wr = wid >> 1, wc = wid & 1;
  const int lhi = lane >> 4, llo = lane & 15;

  for (int d = tid; d < DD; d += 256) aL[d] = Vp[(size_t)i * DD + d];
  if (tid < BM) {
    const int j = i + 1 + khalf * BM + tid;
    jrs[tid] = (j > MR) ? MR : j;
  }
  __syncthreads();

  f32x4 acc[4][4];
#pragma unroll
  for (int a = 0; a < 4; ++a)
#pragma unroll
    for (int b = 0; b < 4; ++b) acc[a][b] = (f32x4){0.f, 0.f, 0.f, 0.f};

  char* Ab = (char*)As;
  char* Bb = (char*)Bs;

  for (int kt = 0; kt < NKT; ++kt) {
    const int kg = kt * BK;
    // ---- stage A: compute x = a .* b -> bf16, swizzled store ----
#pragma unroll
    for (int it = 0; it < 4; ++it) {
      const int c = it * 256 + tid;     // 16B-chunk id: row*8 + chunk
      const int row = c >> 3;
      const int cs = c & 7;
      const int kk = cs * 8;
      const int j = jrs[row];
      const float4 b0 = *(const float4*)(Vp + (size_t)j * DD + kg + kk);
      const float4 b1 = *(const float4*)(Vp + (size_t)j * DD + kg + kk + 4);
      const float4 a0 = *(const float4*)(aL + kg + kk);
      const float4 a1 = *(const float4*)(aL + kg + kk + 4);
      bf16x8 xv;
      xv[0] = (short)f2bfu(a0.x * b0.x);
      xv[1] = (short)f2bfu(a0.y * b0.y);
      xv[2] = (short)f2bfu(a0.z * b0.z);
      xv[3] = (short)f2bfu(a0.w * b0.w);
      xv[4] = (short)f2bfu(a1.x * b1.x);
      xv[5] = (short)f2bfu(a1.y * b1.y);
      xv[6] = (short)f2bfu(a1.z * b1.z);
      xv[7] = (short)f2bfu(a1.w * b1.w);
      *(bf16x8*)(Ab + row * 128 + ((cs ^ (row & 7)) << 4)) = xv;
    }
    // ---- stage B: Wt rows, pre-swizzled source, linear LDS store ----
#pragma unroll
    for (int it = 0; it < 4; ++it) {
      const int s = it * 256 + tid;
      const int row = s >> 3;
      const int cs = s & 7;
      const int ce = cs ^ (row & 7);
      const bf16x8 wv = *(const bf16x8*)(Wt + (size_t)(n0 + row) * DD + kg + ce * 8);
      *(bf16x8*)(Bb + s * 16) = wv;
    }
    __syncthreads();
    // ---- MFMA: 2 k-steps of 32 ----
#pragma unroll
    for (int ks = 0; ks < 2; ++ks) {
      bf16x8 af[4], bfr[4];
#pragma unroll
      for (int mi = 0; mi < 4; ++mi) {
        const int row = wr * 64 + mi * 16 + llo;
        const int ch = (ks * 4 + lhi) ^ (row & 7);
        af[mi] = *(const bf16x8*)(Ab + row * 128 + (ch << 4));
      }
#pragma unroll
      for (int ni = 0; ni < 4; ++ni) {
        const int row = wc * 64 + ni * 16 + llo;
        const int ch = (ks * 4 + lhi) ^ (row & 7);
        bfr[ni] = *(const bf16x8*)(Bb + row * 128 + (ch << 4));
      }
#pragma unroll
      for (int mi = 0; mi < 4; ++mi)
#pragma unroll
        for (int ni = 0; ni < 4; ++ni)
          acc[mi][ni] = __builtin_amdgcn_mfma_f32_16x16x32_bf16(af[mi], bfr[ni], acc[mi][ni], 0, 0, 0);
    }
    __syncthreads();
  }

  // ---- epilogue: relu(acc + Ha_i + Hv_j + bp1) . wp2 over this wave's 64 cols ----
  float ha4[4], bpv[4], wpv[4];
  int cg[4];
#pragma unroll
  for (int ni = 0; ni < 4; ++ni) {
    const int col = n0 + wc * 64 + ni * 16 + llo;
    cg[ni] = col;
    ha4[ni] = Ha[(size_t)i * HH + col];
    bpv[ni] = bp1[col];
    wpv[ni] = wp2[col];
  }
#pragma unroll
  for (int mi = 0; mi < 4; ++mi) {
#pragma unroll
    for (int r = 0; r < 4; ++r) {
      const int rowl = wr * 64 + mi * 16 + lhi * 4 + r;
      const int j = jrs[rowl];
      float part = 0.f;
#pragma unroll
      for (int ni = 0; ni < 4; ++ni) {
        const float pre = acc[mi][ni][r] + ha4[ni] + Hv[(size_t)j * HH + cg[ni]] + bpv[ni];
        part += fmaxf(pre, 0.f) * wpv[ni];
      }
      part += __shfl_xor(part, 1, 64);
      part += __shfl_xor(part, 2, 64);
      part += __shfl_xor(part, 4, 64);
      part += __shfl_xor(part, 8, 64);
      if (llo == 0) redp[rowl][wc] = part;   // per-wave column-half partial
    }
  }
  __syncthreads();
  if (tid < BM)
    pp[(size_t)nb * NPAIR + (size_t)mb * BM + tid] = redp[tid][0] + redp[tid][1];
}

// ---------------- K6: sum partials + bias + scores, mask, softmax over 251 ----------------
__global__ __launch_bounds__(256) void softmax_kernel(
    const float* __restrict__ pp, const float* __restrict__ sfin,
    const float* __restrict__ bp2, float* __restrict__ out) {
  __shared__ float red[4];
  const int i = blockIdx.x, tid = threadIdx.x;
  float v;
  if (tid < KNUM) {
    const int jidx = i + 1 + tid;
    const bool valid = jidx < MSEL;
    const int jc = valid ? jidx : MR;
    float s = 0.f;
#pragma unroll
    for (int b = 0; b < 8; ++b) s += pp[(size_t)b * NPAIR + i * PPAD + tid];
    v = valid ? (s + bp2[0] + sfin[jc] + sfin[i]) : -INFINITY;
  } else if (tid == KNUM) v = 0.f;
  else v = -INFINITY;
  float mx = waveMax(v);
  if ((tid & 63) == 0) red[tid >> 6] = mx;
  __syncthreads();
  const float m = fmaxf(fmaxf(red[0], red[1]), fmaxf(red[2], red[3]));
  __syncthreads();
  const float e = (tid <= KNUM) ? expf(v - m) : 0.f;
  float s = waveSum(e);
  if ((tid & 63) == 0) red[tid >> 6] = s;
  __syncthreads();
  const float tot = red[0] + red[1] + red[2] + red[3];
  if (tid <= KNUM) out[i * OUTW + tid] = e / tot;
}

extern "C" void kernel_launch(void* const* d_in, const int* in_sizes, int n_in,
                              void* d_out, int out_size, void* d_ws, size_t ws_size,
                              hipStream_t stream) {
  const float* vectors = (const float*)d_in[0];
  const float* Wm1 = (const float*)d_in[1];
  const float* bm1 = (const float*)d_in[2];
  const float* wm2 = (const float*)d_in[3];
  const float* bm2 = (const float*)d_in[4];
  const float* Wp1 = (const float*)d_in[5];
  const float* bp1 = (const float*)d_in[6];
  const float* wp2 = (const float*)d_in[7];
  const float* bp2 = (const float*)d_in[8];
  const int* sst = (const int*)d_in[9];
  const int* sen = (const int*)d_in[10];
  float* out = (float*)d_out;
  char* ws = (char*)d_ws;

  float* scores = (float*)(ws);                          // 2000 f32
  int*   top    = (int*)(ws + 8192);                     // 400 i32
  int*   perm   = (int*)(ws + 10240);                    // 400 i32
  float* sfin   = (float*)(ws + 12288);                  // 400 f32
  float* Ha     = (float*)(ws + 16384);                  // 400*1024 f32
  float* Hv     = (float*)(ws + 16384 + 1638400);        // 400*1024 f32
  float* Vp     = (float*)(ws + 3293184);                // 400*768 f32
  ushort* Wt    = (ushort*)(ws + 4521984);               // 1024*768 bf16
  float* pp     = (float*)(ws + 6094848);                // 8 * 102144 f32 partials

  scores_kernel<<<NVEC / 8, 256, 0, stream>>>(vectors, Wm1, bm1, wm2, bm2, scores);
  topsort_kernel<<<1, 1024, 0, stream>>>(scores, top);
  lexsort_kernel<<<1, 256, 0, stream>>>(top, sst, sen, scores, perm, sfin);
  wt_kernel<<<dim3(12, 16), 256, 0, stream>>>(Wp1, Wt);
  hab_kernel<<<MSEL / 8, 256, 0, stream>>>(vectors, Wp1, perm, Ha, Hv, Vp);
  pair_kernel<<<dim3(MR * 2, 8), 256, 0, stream>>>(Vp, Wt, bp1, wp2, Ha, Hv, pp);
  softmax_kernel<<<MR, 256, 0, stream>>>(pp, sfin, bp2, out);
}

// Round 4
// 574.163 us; speedup vs baseline: 4.1873x; 1.3661x over previous
//
#include <hip/hip_runtime.h>
#include <hip/hip_bf16.h>
#include <math.h>

#define NVEC 2000
#define DD   768
#define HH   1024
#define KNUM 250
#define MSEL 400
#define MR   399     // m-1 rows
#define OUTW 251
#define PPAD 256                 // padded antecedents per anaphor
#define NPAIR (MR * PPAD)        // 102144 padded pair rows
#define BM 128
#define BN 256
#define BK 64
#define NKT (DD / BK)            // 12
#define NNB (HH / BN)            // 4

typedef short  bf16x8 __attribute__((ext_vector_type(8)));
typedef float  f32x4  __attribute__((ext_vector_type(4)));
typedef unsigned int u32;

__device__ __forceinline__ float waveSum(float p) {
#pragma unroll
  for (int off = 32; off >= 1; off >>= 1) p += __shfl_xor(p, off, 64);
  return p;
}
__device__ __forceinline__ float waveMax(float p) {
#pragma unroll
  for (int off = 32; off >= 1; off >>= 1) p = fmaxf(p, __shfl_xor(p, off, 64));
  return p;
}
__device__ __forceinline__ short f2bf(float f) {
  __hip_bfloat16 h = __float2bfloat16(f);     // RNE; compiler fuses pairs to v_cvt_pk_bf16_f32
  return __builtin_bit_cast(short, h);
}
__device__ __forceinline__ void gload_lds16(const void* g, void* l) {
  __builtin_amdgcn_global_load_lds(
      (const __attribute__((address_space(1))) u32*)g,
      (__attribute__((address_space(3))) u32*)l, 16, 0, 0);
}

// ---------------- K1: scores = relu(V @ Wm1 + bm1) @ wm2 + bm2 ----------------
// 512 threads (8 waves), 8 rows/block, each thread owns 2 contiguous H-cols.
__global__ __launch_bounds__(512) void scores_kernel(
    const float* __restrict__ vectors, const float* __restrict__ Wm1,
    const float* __restrict__ bm1, const float* __restrict__ wm2,
    const float* __restrict__ bm2, float* __restrict__ scores) {
  __shared__ float vrow[8 * DD];
  __shared__ float red[8];
  const int tid = threadIdx.x;
  const int base = blockIdx.x * 8;
  for (int idx = tid; idx < 8 * DD; idx += 512)
    vrow[idx] = vectors[base * DD + idx];
  __syncthreads();
  float acc[8][2];
#pragma unroll
  for (int r = 0; r < 8; ++r) { acc[r][0] = 0.f; acc[r][1] = 0.f; }
#pragma unroll 4
  for (int d = 0; d < DD; ++d) {
    const float2 w = ((const float2*)(Wm1 + d * HH))[tid];
#pragma unroll
    for (int r = 0; r < 8; ++r) {
      const float a = vrow[r * DD + d];
      acc[r][0] += a * w.x; acc[r][1] += a * w.y;
    }
  }
  const float2 b = ((const float2*)bm1)[tid];
  const float2 m = ((const float2*)wm2)[tid];
  const float sc = bm2[0];
  for (int r = 0; r < 8; ++r) {
    float p = fmaxf(acc[r][0] + b.x, 0.f) * m.x + fmaxf(acc[r][1] + b.y, 0.f) * m.y;
    p = waveSum(p);
    if ((tid & 63) == 0) red[tid >> 6] = p;
    __syncthreads();
    if (tid == 0) {
      float t = red[0];
#pragma unroll
      for (int w8 = 1; w8 < 8; ++w8) t += red[w8];
      scores[base + r] = t + sc;
    }
    __syncthreads();
  }
}

// ---------------- K2: bitonic sort (score desc, idx asc) -> top 400 ----------------
__global__ __launch_bounds__(1024) void topsort_kernel(
    const float* __restrict__ scores, int* __restrict__ top) {
  __shared__ float ks[2048];
  __shared__ int   ki[2048];
  const int tid = threadIdx.x;
  for (int e = tid; e < 2048; e += 1024) {
    ks[e] = (e < NVEC) ? scores[e] : -INFINITY;
    ki[e] = e;
  }
  __syncthreads();
  for (int k = 2; k <= 2048; k <<= 1) {
    for (int j = k >> 1; j > 0; j >>= 1) {
      for (int e = tid; e < 2048; e += 1024) {
        const int l = e ^ j;
        if (l > e) {
          const float s1 = ks[e], s2 = ks[l];
          const int i1 = ki[e], i2 = ki[l];
          const bool first = (s1 > s2) || (s1 == s2 && i1 < i2);
          const bool up = ((e & k) == 0);
          if (up ? !first : first) {
            ks[e] = s2; ks[l] = s1; ki[e] = i2; ki[l] = i1;
          }
        }
      }
      __syncthreads();
    }
  }
  if (tid < MSEL) top[tid] = ki[tid];
}

// ---------------- K3: lexsort by (start,end,pos) asc, reversed ----------------
__global__ __launch_bounds__(256) void lexsort_kernel(
    const int* __restrict__ top, const int* __restrict__ sst,
    const int* __restrict__ sen, const float* __restrict__ scores,
    int* __restrict__ perm, float* __restrict__ sfin) {
  __shared__ int s_st[512], s_en[512], s_j[512];
  const int tid = threadIdx.x;
  for (int e = tid; e < 512; e += 256) {
    if (e < MSEL) { const int ti = top[e]; s_st[e] = sst[ti]; s_en[e] = sen[ti]; }
    else { s_st[e] = 0x7fffffff; s_en[e] = 0x7fffffff; }
    s_j[e] = e;
  }
  __syncthreads();
  for (int k = 2; k <= 512; k <<= 1) {
    for (int j = k >> 1; j > 0; j >>= 1) {
      for (int e = tid; e < 512; e += 256) {
        const int l = e ^ j;
        if (l > e) {
          const int a0 = s_st[e], a1 = s_en[e], a2 = s_j[e];
          const int b0 = s_st[l], b1 = s_en[l], b2 = s_j[l];
          const bool first = (a0 < b0) || (a0 == b0 && (a1 < b1 || (a1 == b1 && a2 < b2)));
          const bool up = ((e & k) == 0);
          if (up ? !first : first) {
            s_st[e] = b0; s_en[e] = b1; s_j[e] = b2;
            s_st[l] = a0; s_en[l] = a1; s_j[l] = a2;
          }
        }
      }
      __syncthreads();
    }
  }
  for (int i = tid; i < MSEL; i += 256) {
    const int src = s_j[MSEL - 1 - i];
    const int vi = top[src];
    perm[i] = vi;
    sfin[i] = scores[vi];
  }
}

// ---------------- K4: Ha = v@Wa, Hv = v@Wb (grid (50, 4) = rowgroup x (mat,colhalf)) ----------------
__global__ __launch_bounds__(256) void hab_kernel(
    const float* __restrict__ vectors, const float* __restrict__ Wp1,
    const int* __restrict__ perm, float* __restrict__ Ha, float* __restrict__ Hv,
    float* __restrict__ Vp) {
  __shared__ float vrow[8 * DD];
  const int tid = threadIdx.x;
  const int base = blockIdx.x * 8;
  const int mat = blockIdx.y >> 1;       // 0 = Wa, 1 = Wb
  const int half = blockIdx.y & 1;       // col half
  for (int r = 0; r < 8; ++r) {
    const int pi = perm[base + r];
    for (int d = tid; d < DD; d += 256) {
      const float val = vectors[pi * DD + d];
      vrow[r * DD + d] = val;
      if (blockIdx.y == 0) Vp[(size_t)(base + r) * DD + d] = val;
    }
  }
  __syncthreads();
  float acc[8][2];
#pragma unroll
  for (int r = 0; r < 8; ++r) { acc[r][0] = 0.f; acc[r][1] = 0.f; }
  const float* W = Wp1 + (size_t)mat * DD * HH + half * 512;
#pragma unroll 4
  for (int d = 0; d < DD; ++d) {
    const float2 w = ((const float2*)(W + (size_t)d * HH))[tid];
#pragma unroll
    for (int r = 0; r < 8; ++r) {
      const float a = vrow[r * DD + d];
      acc[r][0] += a * w.x; acc[r][1] += a * w.y;
    }
  }
  float* dst = mat ? Hv : Ha;
  for (int r = 0; r < 8; ++r) {
    const int row = base + r;
    if (mat == 0 && row >= MR) continue;
    ((float2*)(dst + (size_t)row * HH + half * 512))[tid] =
        make_float2(acc[r][0], acc[r][1]);
  }
}

// ---------------- K4b: Wt[n][k] = bf16(Wab[k][n]) (transpose + cast, once) ----------------
__global__ __launch_bounds__(256) void wt_kernel(
    const float* __restrict__ Wp1, ushort* __restrict__ Wt) {
  __shared__ float tile[64][65];
  const int kb = blockIdx.x;   // 12 tiles over K=768
  const int nb = blockIdx.y;   // 16 tiles over N=1024
  const float* Wab = Wp1 + 2 * DD * HH;
  for (int idx = threadIdx.x; idx < 64 * 64; idx += 256) {
    const int kk = idx >> 6, nn = idx & 63;
    tile[kk][nn] = Wab[(size_t)(kb * 64 + kk) * HH + nb * 64 + nn];
  }
  __syncthreads();
  for (int idx = threadIdx.x; idx < 64 * 64; idx += 256) {
    const int nn = idx >> 6, kk = idx & 63;
    Wt[(size_t)(nb * 64 + nn) * DD + kb * 64 + kk] = (ushort)f2bf(tile[kk][nn]);
  }
}

// ---------------- K5: pairwise einsum as bf16 MFMA GEMM, fused relu-dot epilogue ----------------
// Block: 128 pair-rows (one anaphor i, half of its padded 256 k's) x 256 h-cols.
// 4 waves in 2x2 (wr,wc); wave tile 64 rows x 128 cols (acc[4][8]).
__global__ __launch_bounds__(256) void pair_kernel(
    const float* __restrict__ Vp, const ushort* __restrict__ Wt,
    const float* __restrict__ bp1, const float* __restrict__ wp2,
    const float* __restrict__ Ha, const float* __restrict__ Hv,
    float* __restrict__ pp) {
  __shared__ float aL[DD];
  __shared__ int jrs[BM];
  __shared__ __align__(16) ushort As[BM * BK];
  __shared__ __align__(16) ushort Bs[BN * BK];
  __shared__ float redp[BM][2];
  const int tid = threadIdx.x;
  const int mb = blockIdx.x;          // 0..797  (i*2 + khalf)
  const int nb = blockIdx.y;          // 0..3
  const int i = mb >> 1;
  const int khalf = mb & 1;
  const int n0 = nb * BN;
  const int lane = tid & 63;
  const int wid = tid >> 6;
  const int wr = wid >> 1, wc = wid & 1;
  const int lhi = lane >> 4, llo = lane & 15;

  for (int d = tid; d < DD; d += 256) aL[d] = Vp[(size_t)i * DD + d];
  if (tid < BM) {
    const int j = i + 1 + khalf * BM + tid;
    jrs[tid] = (j > MR) ? MR : j;
  }
  __syncthreads();

  f32x4 acc[4][8];
#pragma unroll
  for (int a = 0; a < 4; ++a)
#pragma unroll
    for (int b = 0; b < 8; ++b) acc[a][b] = (f32x4){0.f, 0.f, 0.f, 0.f};

  char* Ab = (char*)As;
  char* Bb = (char*)Bs;

  for (int kt = 0; kt < NKT; ++kt) {
    const int kg = kt * BK;
    // ---- stage B: global_load_lds, pre-swizzled global source, linear LDS dest ----
    // chunk id s = wid*512 + it*64 + lane; LDS slot s holds global chunk (s&7)^(row&7).
#pragma unroll
    for (int it = 0; it < 8; ++it) {
      const int s = wid * 512 + it * 64 + lane;
      const int row = s >> 3;
      const int ce = (s & 7) ^ (row & 7);
      gload_lds16(Wt + (size_t)(n0 + row) * DD + kg + ce * 8,
                  Bb + (wid * 512 + it * 64) * 16);
    }
    // ---- stage A: compute x = a .* b -> bf16, swizzled LDS store ----
#pragma unroll
    for (int it = 0; it < 4; ++it) {
      const int c = it * 256 + tid;     // 16B-chunk id: row*8 + chunk
      const int row = c >> 3;
      const int cs = c & 7;
      const int kk = cs * 8;
      const int j = jrs[row];
      const float4 b0 = *(const float4*)(Vp + (size_t)j * DD + kg + kk);
      const float4 b1 = *(const float4*)(Vp + (size_t)j * DD + kg + kk + 4);
      const float4 a0 = *(const float4*)(aL + kg + kk);
      const float4 a1 = *(const float4*)(aL + kg + kk + 4);
      bf16x8 xv;
      xv[0] = f2bf(a0.x * b0.x);
      xv[1] = f2bf(a0.y * b0.y);
      xv[2] = f2bf(a0.z * b0.z);
      xv[3] = f2bf(a0.w * b0.w);
      xv[4] = f2bf(a1.x * b1.x);
      xv[5] = f2bf(a1.y * b1.y);
      xv[6] = f2bf(a1.z * b1.z);
      xv[7] = f2bf(a1.w * b1.w);
      *(bf16x8*)(Ab + row * 128 + ((cs ^ (row & 7)) << 4)) = xv;
    }
    __syncthreads();
    // ---- MFMA: 2 k-steps of 32; 4x8 fragment grid per wave ----
#pragma unroll
    for (int ks = 0; ks < 2; ++ks) {
      bf16x8 af[4], bfr[8];
#pragma unroll
      for (int mi = 0; mi < 4; ++mi) {
        const int row = wr * 64 + mi * 16 + llo;
        const int ch = (ks * 4 + lhi) ^ (row & 7);
        af[mi] = *(const bf16x8*)(Ab + row * 128 + (ch << 4));
      }
#pragma unroll
      for (int ni = 0; ni < 8; ++ni) {
        const int row = wc * 128 + ni * 16 + llo;
        const int ch = (ks * 4 + lhi) ^ (row & 7);
        bfr[ni] = *(const bf16x8*)(Bb + row * 128 + (ch << 4));
      }
#pragma unroll
      for (int mi = 0; mi < 4; ++mi)
#pragma unroll
        for (int ni = 0; ni < 8; ++ni)
          acc[mi][ni] = __builtin_amdgcn_mfma_f32_16x16x32_bf16(af[mi], bfr[ni], acc[mi][ni], 0, 0, 0);
    }
    __syncthreads();
  }

  // ---- epilogue: relu(acc + Ha_i + Hv_j + bp1) . wp2 over this wave's 128 cols ----
  float hb8[8], wpv[8];
  int cg[8];
#pragma unroll
  for (int ni = 0; ni < 8; ++ni) {
    const int col = n0 + wc * 128 + ni * 16 + llo;
    cg[ni] = col;
    hb8[ni] = Ha[(size_t)i * HH + col] + bp1[col];
    wpv[ni] = wp2[col];
  }
#pragma unroll
  for (int mi = 0; mi < 4; ++mi) {
#pragma unroll
    for (int r = 0; r < 4; ++r) {
      const int rowl = wr * 64 + mi * 16 + lhi * 4 + r;
      const int j = jrs[rowl];
      float part = 0.f;
#pragma unroll
      for (int ni = 0; ni < 8; ++ni) {
        const float pre = acc[mi][ni][r] + hb8[ni] + Hv[(size_t)j * HH + cg[ni]];
        part += fmaxf(pre, 0.f) * wpv[ni];
      }
      part += __shfl_xor(part, 1, 64);
      part += __shfl_xor(part, 2, 64);
      part += __shfl_xor(part, 4, 64);
      part += __shfl_xor(part, 8, 64);
      if (llo == 0) redp[rowl][wc] = part;   // per-wave column-half partial
    }
  }
  __syncthreads();
  if (tid < BM)
    pp[(size_t)nb * NPAIR + (size_t)mb * BM + tid] = redp[tid][0] + redp[tid][1];
}

// ---------------- K6: sum partials + bias + scores, mask, softmax over 251 ----------------
__global__ __launch_bounds__(256) void softmax_kernel(
    const float* __restrict__ pp, const float* __restrict__ sfin,
    const float* __restrict__ bp2, float* __restrict__ out) {
  __shared__ float red[4];
  const int i = blockIdx.x, tid = threadIdx.x;
  float v;
  if (tid < KNUM) {
    const int jidx = i + 1 + tid;
    const bool valid = jidx < MSEL;
    const int jc = valid ? jidx : MR;
    float s = 0.f;
#pragma unroll
    for (int b = 0; b < NNB; ++b) s += pp[(size_t)b * NPAIR + i * PPAD + tid];
    v = valid ? (s + bp2[0] + sfin[jc] + sfin[i]) : -INFINITY;
  } else if (tid == KNUM) v = 0.f;
  else v = -INFINITY;
  float mx = waveMax(v);
  if ((tid & 63) == 0) red[tid >> 6] = mx;
  __syncthreads();
  const float m = fmaxf(fmaxf(red[0], red[1]), fmaxf(red[2], red[3]));
  __syncthreads();
  const float e = (tid <= KNUM) ? expf(v - m) : 0.f;
  float s = waveSum(e);
  if ((tid & 63) == 0) red[tid >> 6] = s;
  __syncthreads();
  const float tot = red[0] + red[1] + red[2] + red[3];
  if (tid <= KNUM) out[i * OUTW + tid] = e / tot;
}

extern "C" void kernel_launch(void* const* d_in, const int* in_sizes, int n_in,
                              void* d_out, int out_size, void* d_ws, size_t ws_size,
                              hipStream_t stream) {
  const float* vectors = (const float*)d_in[0];
  const float* Wm1 = (const float*)d_in[1];
  const float* bm1 = (const float*)d_in[2];
  const float* wm2 = (const float*)d_in[3];
  const float* bm2 = (const float*)d_in[4];
  const float* Wp1 = (const float*)d_in[5];
  const float* bp1 = (const float*)d_in[6];
  const float* wp2 = (const float*)d_in[7];
  const float* bp2 = (const float*)d_in[8];
  const int* sst = (const int*)d_in[9];
  const int* sen = (const int*)d_in[10];
  float* out = (float*)d_out;
  char* ws = (char*)d_ws;

  float* scores = (float*)(ws);                          // 2000 f32
  int*   top    = (int*)(ws + 8192);                     // 400 i32
  int*   perm   = (int*)(ws + 10240);                    // 400 i32
  float* sfin   = (float*)(ws + 12288);                  // 400 f32
  float* Ha     = (float*)(ws + 16384);                  // 400*1024 f32
  float* Hv     = (float*)(ws + 16384 + 1638400);        // 400*1024 f32
  float* Vp     = (float*)(ws + 3293184);                // 400*768 f32
  ushort* Wt    = (ushort*)(ws + 4521984);               // 1024*768 bf16
  float* pp     = (float*)(ws + 6094848);                // 4 * 102144 f32 partials

  scores_kernel<<<NVEC / 8, 512, 0, stream>>>(vectors, Wm1, bm1, wm2, bm2, scores);
  topsort_kernel<<<1, 1024, 0, stream>>>(scores, top);
  lexsort_kernel<<<1, 256, 0, stream>>>(top, sst, sen, scores, perm, sfin);
  wt_kernel<<<dim3(12, 16), 256, 0, stream>>>(Wp1, Wt);
  hab_kernel<<<dim3(MSEL / 8, 4), 256, 0, stream>>>(vectors, Wp1, perm, Ha, Hv, Vp);
  pair_kernel<<<dim3(MR * 2, NNB), 256, 0, stream>>>(Vp, Wt, bp1, wp2, Ha, Hv, pp);
  softmax_kernel<<<MR, 256, 0, stream>>>(pp, sfin, bp2, out);
}